// Round 1
// baseline (723.019 us; speedup 1.0000x reference)
//
#include <hip/hip_runtime.h>
#include <hip/hip_bf16.h>
#include <math.h>

#define HD 128
#define NN 50000
#define NE 500000
#define LN_EPS 1e-5f

typedef __attribute__((ext_vector_type(8))) short short8;
typedef __attribute__((ext_vector_type(4))) float f32x4;

__device__ __forceinline__ unsigned short f2bf(float f) {
    unsigned int u = __float_as_uint(f);
    u = (u + 0x7FFFu + ((u >> 16) & 1u)) >> 16;   // RNE truncate to bf16
    return (unsigned short)u;
}
__device__ __forceinline__ float bf2f(unsigned short b) {
    return __uint_as_float(((unsigned int)b) << 16);
}
__device__ __forceinline__ float gelu_f(float x) {
    return 0.5f * x * (1.0f + erff(x * 0.70710678118654752440f));
}
__device__ __forceinline__ float sigm_f(float x) {
    return 1.0f / (1.0f + __expf(-x));
}

// ---------------------------------------------------------------------------
// K1: node_pre — X = h (N x128) @ [src_W | e1_Wa | e1_Wb] (128 x 384) + bias
//     outputs bf16 tables hswb / a1b (includes e1_b) / b1b
// 6 waves per block; wave w owns 64 output cols; 64 rows per block.
// ---------------------------------------------------------------------------
__global__ __launch_bounds__(384) void node_pre_kernel(
    const float* __restrict__ h,
    const float* __restrict__ src_W, const float* __restrict__ src_b,
    const float* __restrict__ e1_W, const float* __restrict__ e1_b,
    unsigned short* __restrict__ hswb,
    unsigned short* __restrict__ a1b,
    unsigned short* __restrict__ b1b)
{
    const int lane = threadIdx.x & 63;
    const int w = threadIdx.x >> 6;           // 0..5
    const int lo = lane & 15, hi = lane >> 4;
    const int m0 = blockIdx.x * 64;

    // B fragments in registers: B[k][c], lane holds k = kk*32 + hi*8 + j, c = base+lo
    short8 bf[4][4];
    #pragma unroll
    for (int nn = 0; nn < 4; ++nn) {
        const int c = w * 64 + nn * 16 + lo;   // 0..383
        #pragma unroll
        for (int kk = 0; kk < 4; ++kk) {
            short8 v;
            #pragma unroll
            for (int j = 0; j < 8; ++j) {
                const int k = kk * 32 + hi * 8 + j;
                float wv;
                if (c < 128)      wv = src_W[k * 128 + c];
                else if (c < 256) wv = e1_W[k * 128 + (c - 128)];
                else              wv = e1_W[(128 + k) * 128 + (c - 256)];
                v[j] = (short)f2bf(wv);
            }
            bf[kk][nn] = v;
        }
    }

    f32x4 acc[4][4];
    #pragma unroll
    for (int mm = 0; mm < 4; ++mm)
        #pragma unroll
        for (int nn = 0; nn < 4; ++nn)
            acc[mm][nn] = (f32x4){0.f, 0.f, 0.f, 0.f};

    #pragma unroll
    for (int mm = 0; mm < 4; ++mm) {
        int row = m0 + mm * 16 + lo;
        if (row >= NN) row = NN - 1;           // clamp, stores are guarded
        short8 af[4];
        #pragma unroll
        for (int kk = 0; kk < 4; ++kk) {
            const float* p = h + row * 128 + kk * 32 + hi * 8;
            short8 v;
            #pragma unroll
            for (int j = 0; j < 8; ++j) v[j] = (short)f2bf(p[j]);
            af[kk] = v;
        }
        #pragma unroll
        for (int nn = 0; nn < 4; ++nn)
            #pragma unroll
            for (int kk = 0; kk < 4; ++kk)
                acc[mm][nn] = __builtin_amdgcn_mfma_f32_16x16x32_bf16(
                    af[kk], bf[kk][nn], acc[mm][nn], 0, 0, 0);
    }

    #pragma unroll
    for (int mm = 0; mm < 4; ++mm) {
        #pragma unroll
        for (int nn = 0; nn < 4; ++nn) {
            const int c = w * 64 + nn * 16 + lo;
            #pragma unroll
            for (int r = 0; r < 4; ++r) {
                const int row = m0 + mm * 16 + hi * 4 + r;  // C/D: row = 4*(l>>4)+r
                if (row < NN) {
                    const float v = acc[mm][nn][r];
                    if (c < 128)      hswb[row * 128 + c]       = f2bf(v + src_b[c]);
                    else if (c < 256) a1b [row * 128 + (c-128)] = f2bf(v + e1_b[c-128]);
                    else              b1b [row * 128 + (c-256)] = f2bf(v);
                }
            }
        }
    }
}

// ---------------------------------------------------------------------------
// K3: edge kernel — per 64-edge tile:
//   phase A (vector): t = a1[src] + b1[dst] + ea@e1_Wc; hid = gelu(t) -> LDS (bf16, XOR-swizzled)
//   phase B (MFMA):  ctx = hid @ e2_W, wave w owns gate cols [w*32,w*32+32) and matching shift
//   epilogue: msg = sigmoid(gate+b)*hsw[src] + shift+b; atomic scatter to agg[dst]
// B-fragments of e2_W live in registers across a grid-stride loop over tiles.
// ---------------------------------------------------------------------------
__global__ __launch_bounds__(256, 2) void edge_kernel(
    const float* __restrict__ edge_attr, const int* __restrict__ edge_index,
    const float* __restrict__ e1_W, const float* __restrict__ e2_W, const float* __restrict__ e2_b,
    const unsigned short* __restrict__ hswb,
    const unsigned short* __restrict__ a1b, const unsigned short* __restrict__ b1b,
    float* __restrict__ agg, float* __restrict__ indeg, int nblocks)
{
    __shared__ unsigned int hid32[64 * 64];   // 64 rows x 128 bf16, 16B-chunk XOR swizzle
    __shared__ int src_lds[64];
    __shared__ int dst_lds[64];

    const int lane = threadIdx.x & 63;
    const int w = __builtin_amdgcn_readfirstlane(threadIdx.x >> 6);  // 0..3 (SGPR)
    const int lo = lane & 15, hi = lane >> 4;

    // e1_Wc columns for this lane's two hid cols (2*lane, 2*lane+1)
    float e1c0[16], e1c1[16];
    #pragma unroll
    for (int k = 0; k < 16; ++k) {
        e1c0[k] = e1_W[(256 + k) * 128 + 2 * lane];
        e1c1[k] = e1_W[(256 + k) * 128 + 2 * lane + 1];
    }

    // e2_W B-fragments: wave w n-tiles {w*32, w*32+16, 128+w*32, 128+w*32+16}
    short8 bf[4][4];
    #pragma unroll
    for (int nn = 0; nn < 4; ++nn) {
        const int nbase = (nn < 2) ? (w * 32 + nn * 16) : (128 + w * 32 + (nn - 2) * 16);
        const int n = nbase + lo;
        #pragma unroll
        for (int kk = 0; kk < 4; ++kk) {
            short8 v;
            #pragma unroll
            for (int j = 0; j < 8; ++j) {
                const int k = kk * 32 + hi * 8 + j;
                v[j] = (short)f2bf(e2_W[k * 256 + n]);
            }
            bf[kk][nn] = v;
        }
    }
    float bg[2], bs[2];
    #pragma unroll
    for (int nn = 0; nn < 2; ++nn) {
        bg[nn] = e2_b[w * 32 + nn * 16 + lo];
        bs[nn] = e2_b[128 + w * 32 + nn * 16 + lo];
    }

    for (int eb = blockIdx.x; eb < nblocks; eb += gridDim.x) {
        // ---- phase A ----
        for (int ee = 0; ee < 16; ++ee) {
            const int er = w * 16 + ee;
            const int e = eb * 64 + er;
            if (e < NE) {
                const int s = edge_index[2 * e];
                const int d = edge_index[2 * e + 1];
                if (lane == 0) {
                    src_lds[er] = s;
                    dst_lds[er] = d;
                    unsafeAtomicAdd(&indeg[d], 1.0f);
                }
                const unsigned int av = *(const unsigned int*)(a1b + s * 128 + 2 * lane);
                const unsigned int bv = *(const unsigned int*)(b1b + d * 128 + 2 * lane);
                float t0 = bf2f((unsigned short)(av & 0xFFFFu)) + bf2f((unsigned short)(bv & 0xFFFFu));
                float t1 = bf2f((unsigned short)(av >> 16))     + bf2f((unsigned short)(bv >> 16));
                #pragma unroll
                for (int k = 0; k < 16; ++k) {
                    const float ea = edge_attr[e * 16 + k];
                    t0 += ea * e1c0[k];
                    t1 += ea * e1c1[k];
                }
                t0 = gelu_f(t0);
                t1 = gelu_f(t1);
                const unsigned int hv = (unsigned int)f2bf(t0) | ((unsigned int)f2bf(t1) << 16);
                const int chunk = (lane >> 2) ^ (er & 7);     // swizzle 16B chunks
                hid32[er * 64 + chunk * 4 + (lane & 3)] = hv;
            }
        }
        __syncthreads();

        // ---- phase B: 64 MFMA per wave ----
        f32x4 acc[4][4];
        #pragma unroll
        for (int mm = 0; mm < 4; ++mm)
            #pragma unroll
            for (int nn = 0; nn < 4; ++nn)
                acc[mm][nn] = (f32x4){0.f, 0.f, 0.f, 0.f};

        #pragma unroll
        for (int mm = 0; mm < 4; ++mm) {
            const int row = mm * 16 + lo;
            short8 af[4];
            #pragma unroll
            for (int kk = 0; kk < 4; ++kk) {
                const int sb = ((kk * 4 + hi) ^ (row & 7)) << 4;  // swizzled byte offset
                af[kk] = *(const short8*)((const char*)hid32 + row * 256 + sb);
            }
            #pragma unroll
            for (int nn = 0; nn < 4; ++nn)
                #pragma unroll
                for (int kk = 0; kk < 4; ++kk)
                    acc[mm][nn] = __builtin_amdgcn_mfma_f32_16x16x32_bf16(
                        af[kk], bf[kk][nn], acc[mm][nn], 0, 0, 0);
        }

        // ---- epilogue: gate/shift align in-lane (nn vs nn+2) ----
        #pragma unroll
        for (int mm = 0; mm < 4; ++mm) {
            #pragma unroll
            for (int r = 0; r < 4; ++r) {
                const int er = mm * 16 + hi * 4 + r;
                const int e = eb * 64 + er;
                if (e < NE) {
                    const int s = src_lds[er];
                    const int d = dst_lds[er];
                    #pragma unroll
                    for (int nn = 0; nn < 2; ++nn) {
                        const int c = w * 32 + nn * 16 + lo;
                        const float g  = acc[mm][nn][r]     + bg[nn];
                        const float sh = acc[mm][nn + 2][r] + bs[nn];
                        const float hv = bf2f(hswb[s * 128 + c]);
                        const float msg = sigm_f(g) * hv + sh;
                        unsafeAtomicAdd(&agg[d * 128 + c], msg);
                    }
                }
            }
        }
        __syncthreads();
    }
}

// ---------------------------------------------------------------------------
// K4: node_post — update = [h | agg/indeg] (N x 256) @ [self_W; agg_W] (256 x 128) + biases
//     x = h + gelu(update); LayerNorm(x) -> out
// ---------------------------------------------------------------------------
__global__ __launch_bounds__(256) void node_post_kernel(
    const float* __restrict__ h,
    const float* __restrict__ self_W, const float* __restrict__ self_b,
    const float* __restrict__ agg_W, const float* __restrict__ agg_b,
    const float* __restrict__ ln_g, const float* __restrict__ ln_b,
    const float* __restrict__ agg, const float* __restrict__ indeg,
    float* __restrict__ out)
{
    __shared__ float x_lds[64 * 129];
    const int lane = threadIdx.x & 63;
    const int w = threadIdx.x >> 6;          // 0..3
    const int lo = lane & 15, hi = lane >> 4;
    const int m0 = blockIdx.x * 64;

    short8 bf[8][2];
    #pragma unroll
    for (int nn = 0; nn < 2; ++nn) {
        const int c = w * 32 + nn * 16 + lo;  // 0..127
        #pragma unroll
        for (int kk = 0; kk < 8; ++kk) {
            short8 v;
            #pragma unroll
            for (int j = 0; j < 8; ++j) {
                const int k = kk * 32 + hi * 8 + j;  // 0..255
                const float wv = (k < 128) ? self_W[k * 128 + c] : agg_W[(k - 128) * 128 + c];
                v[j] = (short)f2bf(wv);
            }
            bf[kk][nn] = v;
        }
    }

    f32x4 acc[4][2];
    #pragma unroll
    for (int mm = 0; mm < 4; ++mm)
        #pragma unroll
        for (int nn = 0; nn < 2; ++nn)
            acc[mm][nn] = (f32x4){0.f, 0.f, 0.f, 0.f};

    #pragma unroll
    for (int mm = 0; mm < 4; ++mm) {
        int row = m0 + mm * 16 + lo;
        if (row >= NN) row = NN - 1;
        const float rdeg = 1.0f / fmaxf(indeg[row], 1.0f);
        short8 af[8];
        #pragma unroll
        for (int kk = 0; kk < 4; ++kk) {
            const float* p = h + row * 128 + kk * 32 + hi * 8;
            short8 v;
            #pragma unroll
            for (int j = 0; j < 8; ++j) v[j] = (short)f2bf(p[j]);
            af[kk] = v;
        }
        #pragma unroll
        for (int kk = 4; kk < 8; ++kk) {
            const float* p = agg + row * 128 + (kk - 4) * 32 + hi * 8;
            short8 v;
            #pragma unroll
            for (int j = 0; j < 8; ++j) v[j] = (short)f2bf(p[j] * rdeg);
            af[kk] = v;
        }
        #pragma unroll
        for (int nn = 0; nn < 2; ++nn)
            #pragma unroll
            for (int kk = 0; kk < 8; ++kk)
                acc[mm][nn] = __builtin_amdgcn_mfma_f32_16x16x32_bf16(
                    af[kk], bf[kk][nn], acc[mm][nn], 0, 0, 0);
    }

    #pragma unroll
    for (int mm = 0; mm < 4; ++mm) {
        #pragma unroll
        for (int nn = 0; nn < 2; ++nn) {
            const int c = w * 32 + nn * 16 + lo;
            const float bsum = self_b[c] + agg_b[c];
            #pragma unroll
            for (int r = 0; r < 4; ++r) {
                const int rl = mm * 16 + hi * 4 + r;
                int row = m0 + rl;
                if (row >= NN) row = NN - 1;
                const float upd = acc[mm][nn][r] + bsum;
                const float xv = h[row * 128 + c] + gelu_f(upd);
                x_lds[rl * 129 + c] = xv;
            }
        }
    }
    __syncthreads();

    // LayerNorm: 4 threads per row
    const int rrow = threadIdx.x >> 2;
    const int part = threadIdx.x & 3;
    float sum = 0.f, ss = 0.f;
    #pragma unroll
    for (int i = 0; i < 32; ++i) {
        const float v = x_lds[rrow * 129 + part * 32 + i];
        sum += v; ss += v * v;
    }
    sum += __shfl_xor(sum, 1); ss += __shfl_xor(ss, 1);
    sum += __shfl_xor(sum, 2); ss += __shfl_xor(ss, 2);
    const float mu = sum * (1.0f / 128.0f);
    const float var = ss * (1.0f / 128.0f) - mu * mu;
    const float rstd = rsqrtf(var + LN_EPS);
    const int grow = m0 + rrow;
    if (grow < NN) {
        #pragma unroll
        for (int i = 0; i < 32; ++i) {
            const int c = part * 32 + i;
            const float v = x_lds[rrow * 129 + c];
            out[grow * 128 + c] = (v - mu) * rstd * ln_g[c] + ln_b[c];
        }
    }
}

// ---------------------------------------------------------------------------
extern "C" void kernel_launch(void* const* d_in, const int* in_sizes, int n_in,
                              void* d_out, int out_size, void* d_ws, size_t ws_size,
                              hipStream_t stream) {
    const float* h         = (const float*)d_in[0];
    const float* edge_attr = (const float*)d_in[1];
    const int*   edge_index= (const int*)  d_in[2];
    const float* src_W     = (const float*)d_in[3];
    const float* src_b     = (const float*)d_in[4];
    const float* e1_W      = (const float*)d_in[5];
    const float* e1_b      = (const float*)d_in[6];
    const float* e2_W      = (const float*)d_in[7];
    const float* e2_b      = (const float*)d_in[8];
    const float* self_W    = (const float*)d_in[9];
    const float* self_b    = (const float*)d_in[10];
    const float* agg_W     = (const float*)d_in[11];
    const float* agg_b     = (const float*)d_in[12];
    const float* ln_g      = (const float*)d_in[13];
    const float* ln_b      = (const float*)d_in[14];
    float* out = (float*)d_out;

    char* ws = (char*)d_ws;
    unsigned short* hswb = (unsigned short*)(ws);               // N*128 bf16 = 12.8 MB
    unsigned short* a1b  = (unsigned short*)(ws + 12800000);    // N*128 bf16
    unsigned short* b1b  = (unsigned short*)(ws + 25600000);    // N*128 bf16
    float* agg   = (float*)(ws + 38400000);                     // N*128 f32 = 25.6 MB
    float* indeg = (float*)(ws + 64000000);                     // N f32

    // zero agg + indeg (contiguous)
    hipMemsetAsync(agg, 0, 25600000 + 200000, stream);

    node_pre_kernel<<<(NN + 63) / 64, 384, 0, stream>>>(
        h, src_W, src_b, e1_W, e1_b, hswb, a1b, b1b);

    const int nblocks = (NE + 63) / 64;   // 7813
    edge_kernel<<<2608, 256, 0, stream>>>(
        edge_attr, edge_index, e1_W, e2_W, e2_b, hswb, a1b, b1b, agg, indeg, nblocks);

    node_post_kernel<<<(NN + 63) / 64, 256, 0, stream>>>(
        h, self_W, self_b, agg_W, agg_b, ln_g, ln_b, agg, indeg, out);
}